// Round 6
// baseline (105.196 us; speedup 1.0000x reference)
//
#include <hip/hip_runtime.h>

#define BB 4096
#define TN 512
#define IN 13
#define HN 7
#define FFD 512
#define CT 16            // timesteps per chunk
#define NCK (TN / CT)    // 32 chunks
#define GPB 2            // chains per block

// cross-lane helpers (defined semantics -> no compiler-reordering hazard)
#define SWZ(v, imm) __int_as_float(__builtin_amdgcn_ds_swizzle(__float_as_int(v), (imm)))
#define QB(v, q)    __int_as_float(__builtin_amdgcn_mov_dpp(__float_as_int(v), (q)*0x55, 0xF, 0xF, true))

// packed dual-fp32 FMA (CDNA2+): d.{x,y} = a.{x,y}*b.{x,y} + c.{x,y}
__device__ __forceinline__ float2 pkfma(float2 a, float2 b, float2 c) {
    float2 d;
    asm("v_pk_fma_f32 %0, %1, %2, %3" : "=v"(d) : "v"(a), "v"(b), "v"(c));
    return d;
}

__global__ __launch_bounds__(128, 7)
void lstm_fused(const float* __restrict__ x,
                const float* __restrict__ w_ih,
                const float* __restrict__ w_hh,
                const float* __restrict__ b_ih,
                const float* __restrict__ b_hh,
                const float* __restrict__ fc1_w,
                const float* __restrict__ fc1_b,
                const float* __restrict__ fc_w,
                const float* __restrict__ fc_b,
                float* __restrict__ out)
{
    __shared__ float2 xd2[2][CT/2][64];   // scaled gate pre-activation, step-pairs, dbuf
    __shared__ float  xs[IN][GPB][CT];    // staged x, COLUMN-major (col, chain, step)

    const int tid  = threadIdx.x;
    const int wid  = tid >> 6;            // 0 = consumer wave, 1 = producer wave
    const int l64  = tid & 63;
    const int grp  = l64 >> 5;
    const int lane = l64 & 31;
    const int b    = blockIdx.x * GPB + grp;

    // gate layout: quad j = hidden unit j, tau = lane&3 (0=i,1=f,2=g,3=o)
    const int tau = lane & 3;
    const int ju  = lane >> 2;
    const int jj  = (ju < HN) ? ju : (HN - 1);
    const int row = tau * HN + jj;

    const float L2E  = 1.4426950408889634f;
    const bool  is_tanh = (tau == 2);
    const float kmul = is_tanh ? (-2.0f * L2E) : (-L2E);  // folded into weights
    const float sc   = is_tanh ?  2.0f : 1.0f;
    const float offc = is_tanh ? -1.0f : 0.0f;

    // ---------------- producer-only state ----------------
    const int s_st = lane & 15;           // step this lane stages
    const int h_st = (lane >> 4) & 1;     // column half (0: cols 0-6, 1: cols 7-12)
    const int cb   = h_st * 7;
    float2 w2[IN];
    float2 bias2;
    float  p[7];

    // ---------------- consumer-only state ----------------
    float whh[HN];

    if (wid == 1) {
#pragma unroll
        for (int i = 0; i < IN; ++i) {
            const float w = kmul * w_ih[row * IN + i];
            w2[i] = make_float2(w, w);
        }
        const float bsum = kmul * (b_ih[row] + b_hh[row]);
        bias2 = make_float2(bsum, bsum);
    } else {
#pragma unroll
        for (int k = 0; k < HN; ++k) whh[k] = kmul * w_hh[row * HN + k];
        __builtin_amdgcn_s_setprio(1);    // favor the latency-critical recurrence
    }

    float h0 = 0.f, h1 = 0.f, h2 = 0.f, h3 = 0.f, h4 = 0.f, h5 = 0.f, h6 = 0.f;
    float cval = 0.0f;

    // ---------------- prologue: produce chunk 0, preload chunk 1 ----------------
    if (wid == 1) {
        const float* src0 = x + ((long)b * TN + s_st) * IN + cb;
#pragma unroll
        for (int c = 0; c < 6; ++c) p[c] = src0[c];
        if (h_st == 0) p[6] = src0[6];
        // write xs (col-major)
#pragma unroll
        for (int c = 0; c < 6; ++c) xs[cb + c][grp][s_st] = p[c];
        if (h_st == 0) xs[cb + 6][grp][s_st] = p[6];
        // preload chunk 1 (latency hidden under projection below)
        {
            const float* src1 = x + ((long)b * TN + CT + s_st) * IN + cb;
#pragma unroll
            for (int c = 0; c < 6; ++c) p[c] = src1[c];
            if (h_st == 0) p[6] = src1[6];
        }
        // project chunk 0 -> xd2[0]
#pragma unroll
        for (int q = 0; q < CT; q += 4) {
            float2 accA = bias2, accB = bias2;
#pragma unroll
            for (int i = 0; i < IN; ++i) {
                const float4 xv = *(const float4*)&xs[i][grp][q];
                accA = pkfma(w2[i], make_float2(xv.x, xv.y), accA);
                accB = pkfma(w2[i], make_float2(xv.z, xv.w), accB);
            }
            xd2[0][(q >> 1) + 0][l64] = accA;
            xd2[0][(q >> 1) + 1][l64] = accB;
        }
    }
    __syncthreads();

    // ---------------- main pipeline ----------------
    for (int ck = 0; ck < NCK; ++ck) {
        if (wid == 1) {
            const int nk = ck + 1;                 // chunk to produce now
            if (nk < NCK) {
                // 1) commit preloaded registers -> xs
#pragma unroll
                for (int c = 0; c < 6; ++c) xs[cb + c][grp][s_st] = p[c];
                if (h_st == 0) xs[cb + 6][grp][s_st] = p[6];
                // 2) issue loads for nk+1 (consumed next iteration)
                if (nk + 1 < NCK) {
                    const float* src = x + ((long)b * TN + (nk + 1) * CT + s_st) * IN + cb;
#pragma unroll
                    for (int c = 0; c < 6; ++c) p[c] = src[c];
                    if (h_st == 0) p[6] = src[6];
                }
                // 3) project chunk nk -> xd2[nk&1] (packed dual-FMA)
                const int buf = nk & 1;
#pragma unroll
                for (int q = 0; q < CT; q += 4) {
                    float2 accA = bias2, accB = bias2;
#pragma unroll
                    for (int i = 0; i < IN; ++i) {
                        const float4 xv = *(const float4*)&xs[i][grp][q];
                        accA = pkfma(w2[i], make_float2(xv.x, xv.y), accA);
                        accB = pkfma(w2[i], make_float2(xv.z, xv.w), accB);
                    }
                    xd2[buf][(q >> 1) + 0][l64] = accA;
                    xd2[buf][(q >> 1) + 1][l64] = accB;
                }
            }
        } else {
            const int buf = ck & 1;
            float xr[CT];
#pragma unroll
            for (int pq = 0; pq < CT / 2; ++pq) {
                const float2 v = xd2[buf][pq][l64];
                xr[2 * pq]     = v.x;
                xr[2 * pq + 1] = v.y;
            }
#pragma unroll
            for (int s = 0; s < CT; ++s) {
                // scaled pre-activation: xr already holds kmul*(xW+b); whh pre-scaled
                float s0 = fmaf(whh[0], h0, xr[s]);
                s0 = fmaf(whh[1], h1, s0);
                s0 = fmaf(whh[2], h2, s0);
                s0 = fmaf(whh[3], h3, s0);
                float s1 = whh[4] * h4;
                s1 = fmaf(whh[5], h5, s1);
                s1 = fmaf(whh[6], h6, s1);
                const float sg = s0 + s1;

                float e   = __builtin_amdgcn_exp2f(sg);
                float val = fmaf(__builtin_amdgcn_rcpf(1.0f + e), sc, offc);

                const float iv = QB(val, 0);
                const float fv = QB(val, 1);
                const float gv = QB(val, 2);
                const float ov = QB(val, 3);

                cval = fmaf(fv, cval, iv * gv);
                float e2 = __builtin_amdgcn_exp2f(-2.0f * L2E * cval);
                float th = fmaf(__builtin_amdgcn_rcpf(1.0f + e2), 2.0f, -1.0f);
                const float hq = ov * th;

                h0 = SWZ(hq, (0  << 5));
                h1 = SWZ(hq, (4  << 5));
                h2 = SWZ(hq, (8  << 5));
                h3 = SWZ(hq, (12 << 5));
                h4 = SWZ(hq, (16 << 5));
                h5 = SWZ(hq, (20 << 5));
                h6 = SWZ(hq, (24 << 5));
            }
        }
        __syncthreads();
    }

    if (wid == 1) return;

    // epilogue (consumer): relu -> fc1(512x7) -> relu -> fc(1x512)
    float hb[HN] = { fmaxf(h0,0.f), fmaxf(h1,0.f), fmaxf(h2,0.f), fmaxf(h3,0.f),
                     fmaxf(h4,0.f), fmaxf(h5,0.f), fmaxf(h6,0.f) };

    float acc = 0.0f;
#pragma unroll
    for (int k = 0; k < FFD / 32; ++k) {
        const int r = lane + (k << 5);
        float s = fc1_b[r];
#pragma unroll
        for (int j = 0; j < HN; ++j) s = fmaf(fc1_w[r * HN + j], hb[j], s);
        s = fmaxf(s, 0.0f);
        acc = fmaf(fc_w[r], s, acc);
    }
#pragma unroll
    for (int o = 16; o >= 1; o >>= 1) acc += __shfl_xor(acc, o, 32);
    if (lane == 0) out[b] = acc + fc_b[0];
}

extern "C" void kernel_launch(void* const* d_in, const int* in_sizes, int n_in,
                              void* d_out, int out_size, void* d_ws, size_t ws_size,
                              hipStream_t stream) {
    const float* x     = (const float*)d_in[0];
    const float* w_ih  = (const float*)d_in[1];
    const float* w_hh  = (const float*)d_in[2];
    const float* b_ih  = (const float*)d_in[3];
    const float* b_hh  = (const float*)d_in[4];
    const float* fc1_w = (const float*)d_in[5];
    const float* fc1_b = (const float*)d_in[6];
    const float* fc_w  = (const float*)d_in[7];
    const float* fc_b  = (const float*)d_in[8];
    float* out = (float*)d_out;

    dim3 grid(BB / GPB);   // 2048 blocks x (1 consumer + 1 producer wave)
    dim3 block(128);
    hipLaunchKernelGGL(lstm_fused, grid, block, 0, stream,
                       x, w_ih, w_hh, b_ih, b_hh, fc1_w, fc1_b, fc_w, fc_b, out);
}